// Round 3
// baseline (120.530 us; speedup 1.0000x reference)
//
#include <hip/hip_runtime.h>

#define BB 16
#define NN 4096
#define CC 6
#define NSEG (BB * NN)          // 65536 rows per direction
#define IPT 8                   // i-points per thread
#define ISPLIT 2                // 4096 / (IPT*256)
#define JSPLIT 16
#define JPB (NN / JSPLIT)       // 256 j per block
#define FLTMAX_BITS 0x7F7FFFFFu

// ws layout: [0, 2MB) : float4 yt[2][16][4096]  = (-2y0,-2y1,-2y2,ry)
//            [2MB, 2.5MB) : uint mins[2][16][4096] (uint-ordered, clamped >=0)

// Build streamed point table + init mins. grid 512 x 256.
__global__ __launch_bounds__(256) void chamfer_prep_kernel(
    const float* __restrict__ xg, const float* __restrict__ yg,
    float4* __restrict__ yt, unsigned int* __restrict__ mins)
{
    const int p = blockIdx.x * 256 + threadIdx.x;     // 0 .. 131071
    const int dir = p >> 16;
    const int rem = p & (NSEG - 1);
    const float* __restrict__ S = dir ? xg : yg;      // dir0 mins over y, dir1 over x
    const float a0 = S[(size_t)rem * CC + 0];
    const float a1 = S[(size_t)rem * CC + 1];
    const float a2 = S[(size_t)rem * CC + 2];
    const float r  = fmaf(a0, a0, fmaf(a1, a1, a2 * a2));
    yt[p] = make_float4(-2.f * a0, -2.f * a1, -2.f * a2, r);
    mins[p] = FLTMAX_BITS;
}

// grid = dir(1b) | jsp(4b) | isp(1b) | b(4b) = 1024 blocks x 256 threads
__global__ __launch_bounds__(256, 4) void chamfer_min_kernel(
    const float* __restrict__ xg, const float* __restrict__ yg,
    const float4* __restrict__ yt, unsigned int* __restrict__ mins)
{
    const int bid = blockIdx.x;
    const int dir = bid & 1;
    const int jsp = (bid >> 1) & 15;
    const int isp = (bid >> 5) & 1;
    const int b   = bid >> 6;

    const float* __restrict__ X = dir ? yg : xg;      // rows we take the min FOR
    const int tid = threadIdx.x;
    const size_t xb = (size_t)b * NN;

    float x0[IPT], x1[IPT], x2[IPT], rx[IPT], m[IPT];
    #pragma unroll
    for (int r = 0; r < IPT; ++r) {
        const int i = isp * (IPT * 256) + r * 256 + tid;
        x0[r] = X[(xb + i) * CC + 0];
        x1[r] = X[(xb + i) * CC + 1];
        x2[r] = X[(xb + i) * CC + 2];
        rx[r] = fmaf(x0[r], x0[r], fmaf(x1[r], x1[r], x2[r] * x2[r]));
        m[r]  = 3.4e38f;
    }

    // uniform (scalar) stream of the opposing point cloud
    const int jbase = (dir << 16) + (b << 12) + jsp * JPB;   // index into yt
    for (int js = 0; js < JPB; js += 4) {
        const int jj = __builtin_amdgcn_readfirstlane(jbase + js);
        const float4 v0 = yt[jj + 0];
        const float4 v1 = yt[jj + 1];
        const float4 v2 = yt[jj + 2];
        const float4 v3 = yt[jj + 3];
        #pragma unroll
        for (int r = 0; r < IPT; ++r) {
            const float t0 = fmaf(x0[r], v0.x, fmaf(x1[r], v0.y, fmaf(x2[r], v0.z, v0.w)));
            const float t1 = fmaf(x0[r], v1.x, fmaf(x1[r], v1.y, fmaf(x2[r], v1.z, v1.w)));
            const float t2 = fmaf(x0[r], v2.x, fmaf(x1[r], v2.y, fmaf(x2[r], v2.z, v2.w)));
            const float t3 = fmaf(x0[r], v3.x, fmaf(x1[r], v3.y, fmaf(x2[r], v3.z, v3.w)));
            m[r] = fminf(m[r], fminf(t0, t1));   // -> v_min3
            m[r] = fminf(m[r], fminf(t2, t3));   // -> v_min3
        }
    }

    unsigned int* __restrict__ row = mins + (size_t)dir * NSEG + (size_t)b * NN;
    #pragma unroll
    for (int r = 0; r < IPT; ++r) {
        const int i = isp * (IPT * 256) + r * 256 + tid;
        const float d = fmaxf(rx[r] + m[r], 0.0f);   // true min >= 0; clamp fp noise
        atomicMin(&row[i], __float_as_uint(d));
    }
}

// 128 blocks x 256: sum all mins, one atomicAdd per block
__global__ __launch_bounds__(256) void chamfer_reduce_kernel(
    const unsigned int* __restrict__ mins, float* __restrict__ out)
{
    const int TOT = 2 * NSEG;  // 131072
    float s = 0.0f;
    for (int p = blockIdx.x * 256 + threadIdx.x; p < TOT; p += 128 * 256)
        s += __uint_as_float(mins[p]);

    for (int off = 32; off > 0; off >>= 1)
        s += __shfl_down(s, off, 64);

    __shared__ float wsum[4];
    const int wave = threadIdx.x >> 6;
    if ((threadIdx.x & 63) == 0) wsum[wave] = s;
    __syncthreads();
    if (threadIdx.x == 0)
        atomicAdd(out, (wsum[0] + wsum[1] + wsum[2] + wsum[3]) * (1.0f / NSEG));
}

extern "C" void kernel_launch(void* const* d_in, const int* in_sizes, int n_in,
                              void* d_out, int out_size, void* d_ws, size_t ws_size,
                              hipStream_t stream) {
    const float* x = (const float*)d_in[0];
    const float* y = (const float*)d_in[1];
    float* out = (float*)d_out;

    float4* yt = (float4*)d_ws;
    unsigned int* mins = (unsigned int*)((char*)d_ws + (size_t)2 * NSEG * sizeof(float4));

    hipMemsetAsync(d_out, 0, sizeof(float), stream);

    chamfer_prep_kernel<<<2 * NSEG / 256, 256, 0, stream>>>(x, y, yt, mins);
    chamfer_min_kernel<<<2 * JSPLIT * ISPLIT * BB, 256, 0, stream>>>(x, y, yt, mins);
    chamfer_reduce_kernel<<<128, 256, 0, stream>>>(mins, out);
}

// Round 4
// 109.693 us; speedup vs baseline: 1.0988x; 1.0988x over previous
//
#include <hip/hip_runtime.h>

#define BB 16
#define NN 4096
#define CC 6
#define NSEG (BB * NN)          // 65536 rows per direction
#define IPT 16                  // rows per thread: 1 ds_read serves 16 pairs

// part layout: float part[2][JSP][BB][NN] — partial row-mins (rx + min_t)

template<int JSP>
__global__ __launch_bounds__(256) void chamfer_min_kernel(
    const float* __restrict__ xg, const float* __restrict__ yg,
    float* __restrict__ part)
{
    constexpr int JPB = NN / JSP;       // j's per block
    const int bid = blockIdx.x;
    const int dir = bid & 1;
    const int jsp = (bid >> 1) % JSP;
    const int b   = bid / (2 * JSP);

    const float* __restrict__ X = dir ? yg : xg;   // rows we take the min FOR
    const float* __restrict__ Y = dir ? xg : yg;   // points we min OVER
    const int tid = threadIdx.x;
    const size_t xb = (size_t)b * NN;

    __shared__ float4 ytile[JPB];
    for (int t = tid; t < JPB; t += 256) {
        const int j = jsp * JPB + t;
        const float y0 = Y[(xb + j) * CC + 0];
        const float y1 = Y[(xb + j) * CC + 1];
        const float y2 = Y[(xb + j) * CC + 2];
        ytile[t] = make_float4(-2.f * y0, -2.f * y1, -2.f * y2,
                               fmaf(y0, y0, fmaf(y1, y1, y2 * y2)));
    }

    float x0[IPT], x1[IPT], x2[IPT], rx[IPT], m[IPT];
    #pragma unroll
    for (int r = 0; r < IPT; ++r) {
        const int i = r * 256 + tid;                  // covers all 4096 rows
        const float2 c01 = *(const float2*)&X[(xb + i) * CC];
        const float  c2  = X[(xb + i) * CC + 2];
        x0[r] = c01.x; x1[r] = c01.y; x2[r] = c2;
        rx[r] = fmaf(c01.x, c01.x, fmaf(c01.y, c01.y, c2 * c2));
        m[r]  = 3.4e38f;
    }
    __syncthreads();   // the only barrier: tile staged once

    for (int js = 0; js < JPB; js += 2) {
        const float4 va = ytile[js];
        const float4 vb = ytile[js + 1];
        #pragma unroll
        for (int r = 0; r < IPT; ++r) {
            const float ta = fmaf(x0[r], va.x, fmaf(x1[r], va.y, fmaf(x2[r], va.z, va.w)));
            const float tb = fmaf(x0[r], vb.x, fmaf(x1[r], vb.y, fmaf(x2[r], vb.z, vb.w)));
            m[r] = fminf(m[r], fminf(ta, tb));   // -> v_min3_f32
        }
    }

    float* __restrict__ dst = part + ((size_t)(dir * JSP + jsp) * BB + b) * NN;
    #pragma unroll
    for (int r = 0; r < IPT; ++r)
        dst[r * 256 + tid] = rx[r] + m[r];
}

template<int JSP>
__global__ __launch_bounds__(256) void chamfer_reduce_kernel(
    const float* __restrict__ part, float* __restrict__ out)
{
    float s = 0.0f;
    for (int p = blockIdx.x * 256 + threadIdx.x; p < 2 * NSEG; p += 256 * 256) {
        const int dir = p >> 16;
        const int rem = p & (NSEG - 1);
        const float* base = part + (size_t)dir * JSP * NSEG + rem;
        float v = base[0];
        #pragma unroll
        for (int sg = 1; sg < JSP; ++sg)
            v = fminf(v, base[(size_t)sg * NSEG]);
        s += v;
    }

    for (int off = 32; off > 0; off >>= 1)
        s += __shfl_down(s, off, 64);

    __shared__ float wsum[4];
    const int wave = threadIdx.x >> 6;
    if ((threadIdx.x & 63) == 0) wsum[wave] = s;
    __syncthreads();
    if (threadIdx.x == 0)
        atomicAdd(out, (wsum[0] + wsum[1] + wsum[2] + wsum[3]) * (1.0f / NSEG));
}

extern "C" void kernel_launch(void* const* d_in, const int* in_sizes, int n_in,
                              void* d_out, int out_size, void* d_ws, size_t ws_size,
                              hipStream_t stream) {
    const float* x = (const float*)d_in[0];
    const float* y = (const float*)d_in[1];
    float* out = (float*)d_out;
    float* part = (float*)d_ws;

    hipMemsetAsync(d_out, 0, sizeof(float), stream);

    const size_t segbytes = (size_t)NSEG * sizeof(float);
    if (ws_size >= 2 * 16 * segbytes) {          // 8 MB
        chamfer_min_kernel<16><<<2 * 16 * BB, 256, 0, stream>>>(x, y, part);
        chamfer_reduce_kernel<16><<<256, 256, 0, stream>>>(part, out);
    } else if (ws_size >= 2 * 8 * segbytes) {    // 4 MB
        chamfer_min_kernel<8><<<2 * 8 * BB, 256, 0, stream>>>(x, y, part);
        chamfer_reduce_kernel<8><<<256, 256, 0, stream>>>(part, out);
    } else {                                     // 2 MB
        chamfer_min_kernel<4><<<2 * 4 * BB, 256, 0, stream>>>(x, y, part);
        chamfer_reduce_kernel<4><<<256, 256, 0, stream>>>(part, out);
    }
}

// Round 5
// 105.408 us; speedup vs baseline: 1.1435x; 1.0406x over previous
//
#include <hip/hip_runtime.h>

#define BB 16
#define NN 4096
#define CC 6
#define NSEG (BB * NN)          // 65536 rows per direction
#define IPT 16                  // rows per thread (8 packed pairs)
#define NPR (IPT / 2)

typedef __attribute__((ext_vector_type(2))) float f32x2;

// part layout: float part[2][JSP][BB][NN] — partial row-mins (rx + min_t)

template<int JSP>
__global__ __launch_bounds__(256) void chamfer_min_kernel(
    const float* __restrict__ xg, const float* __restrict__ yg,
    float* __restrict__ part)
{
    constexpr int JPB = NN / JSP;
    const int bid = blockIdx.x;
    const int dir = bid & 1;
    const int jsp = (bid >> 1) % JSP;
    const int b   = bid / (2 * JSP);

    const float* __restrict__ X = dir ? yg : xg;   // rows we take the min FOR
    const float* __restrict__ Y = dir ? xg : yg;   // points we min OVER
    const int tid = threadIdx.x;
    const size_t xb = (size_t)b * NN;

    __shared__ float4 ytile[JPB];                  // (-2y0, -2y1, -2y2, ry)
    for (int t = tid; t < JPB; t += 256) {
        const int j = jsp * JPB + t;
        const float y0 = Y[(xb + j) * CC + 0];
        const float y1 = Y[(xb + j) * CC + 1];
        const float y2 = Y[(xb + j) * CC + 2];
        ytile[t] = make_float4(-2.f * y0, -2.f * y1, -2.f * y2,
                               fmaf(y0, y0, fmaf(y1, y1, y2 * y2)));
    }

    // rows packed in pairs: pair p holds rows (2p)*256+tid and (2p+1)*256+tid
    f32x2 x0p[NPR], x1p[NPR], x2p[NPR];
    float rx[IPT], m[IPT];
    #pragma unroll
    for (int r = 0; r < IPT; ++r) {
        const int i = r * 256 + tid;
        const float2 c01 = *(const float2*)&X[(xb + i) * CC];
        const float  c2  = X[(xb + i) * CC + 2];
        rx[r] = fmaf(c01.x, c01.x, fmaf(c01.y, c01.y, c2 * c2));
        m[r]  = 3.4e38f;
        const int p = r >> 1;
        if ((r & 1) == 0) { x0p[p].x = c01.x; x1p[p].x = c01.y; x2p[p].x = c2; }
        else              { x0p[p].y = c01.x; x1p[p].y = c01.y; x2p[p].y = c2; }
    }
    __syncthreads();   // tile staged once; only barrier

    for (int js = 0; js < JPB; js += 2) {
        const float4 ya = ytile[js];
        const float4 yb = ytile[js + 1];
        const f32x2 Aa = {ya.x, ya.y}, Ba = {ya.z, ya.w};   // (y0',y1'), (y2',ry)
        const f32x2 Ab = {yb.x, yb.y}, Bb = {yb.z, yb.w};
        #pragma unroll
        for (int p = 0; p < NPR; ++p) {
            f32x2 ta, tb;
            // ta = x2p*bcast(y2') + bcast(ry)   [src1: lo-bcast, src2: hi-bcast]
            asm("v_pk_fma_f32 %0, %1, %2, %2 op_sel:[0,0,1] op_sel_hi:[1,0,1]"
                : "=v"(ta) : "v"(x2p[p]), "v"(Ba));
            // ta = x1p*bcast(y1') + ta          [src1: hi-bcast]
            asm("v_pk_fma_f32 %0, %1, %2, %3 op_sel:[0,1,0] op_sel_hi:[1,1,1]"
                : "=v"(ta) : "v"(x1p[p]), "v"(Aa), "0"(ta));
            // ta = x0p*bcast(y0') + ta          [src1: lo-bcast]
            asm("v_pk_fma_f32 %0, %1, %2, %3 op_sel:[0,0,0] op_sel_hi:[1,0,1]"
                : "=v"(ta) : "v"(x0p[p]), "v"(Aa), "0"(ta));

            asm("v_pk_fma_f32 %0, %1, %2, %2 op_sel:[0,0,1] op_sel_hi:[1,0,1]"
                : "=v"(tb) : "v"(x2p[p]), "v"(Bb));
            asm("v_pk_fma_f32 %0, %1, %2, %3 op_sel:[0,1,0] op_sel_hi:[1,1,1]"
                : "=v"(tb) : "v"(x1p[p]), "v"(Ab), "0"(tb));
            asm("v_pk_fma_f32 %0, %1, %2, %3 op_sel:[0,0,0] op_sel_hi:[1,0,1]"
                : "=v"(tb) : "v"(x0p[p]), "v"(Ab), "0"(tb));

            m[2*p]   = fminf(m[2*p],   fminf(ta.x, tb.x));   // -> v_min3_f32
            m[2*p+1] = fminf(m[2*p+1], fminf(ta.y, tb.y));   // -> v_min3_f32
        }
    }

    float* __restrict__ dst = part + ((size_t)(dir * JSP + jsp) * BB + b) * NN;
    #pragma unroll
    for (int r = 0; r < IPT; ++r)
        dst[r * 256 + tid] = rx[r] + m[r];
}

template<int JSP>
__global__ __launch_bounds__(256) void chamfer_reduce_kernel(
    const float* __restrict__ part, float* __restrict__ out)
{
    float s = 0.0f;
    for (int p = blockIdx.x * 256 + threadIdx.x; p < 2 * NSEG; p += 256 * 256) {
        const int dir = p >> 16;
        const int rem = p & (NSEG - 1);
        const float* base = part + (size_t)dir * JSP * NSEG + rem;
        float v = base[0];
        #pragma unroll
        for (int sg = 1; sg < JSP; ++sg)
            v = fminf(v, base[(size_t)sg * NSEG]);
        s += v;
    }

    for (int off = 32; off > 0; off >>= 1)
        s += __shfl_down(s, off, 64);

    __shared__ float wsum[4];
    const int wave = threadIdx.x >> 6;
    if ((threadIdx.x & 63) == 0) wsum[wave] = s;
    __syncthreads();
    if (threadIdx.x == 0)
        atomicAdd(out, (wsum[0] + wsum[1] + wsum[2] + wsum[3]) * (1.0f / NSEG));
}

extern "C" void kernel_launch(void* const* d_in, const int* in_sizes, int n_in,
                              void* d_out, int out_size, void* d_ws, size_t ws_size,
                              hipStream_t stream) {
    const float* x = (const float*)d_in[0];
    const float* y = (const float*)d_in[1];
    float* out = (float*)d_out;
    float* part = (float*)d_ws;

    hipMemsetAsync(d_out, 0, sizeof(float), stream);

    const size_t segbytes = (size_t)NSEG * sizeof(float);
    if (ws_size >= 2 * 16 * segbytes) {          // 8 MB
        chamfer_min_kernel<16><<<2 * 16 * BB, 256, 0, stream>>>(x, y, part);
        chamfer_reduce_kernel<16><<<256, 256, 0, stream>>>(part, out);
    } else if (ws_size >= 2 * 8 * segbytes) {    // 4 MB
        chamfer_min_kernel<8><<<2 * 8 * BB, 256, 0, stream>>>(x, y, part);
        chamfer_reduce_kernel<8><<<256, 256, 0, stream>>>(part, out);
    } else {                                     // 2 MB
        chamfer_min_kernel<4><<<2 * 4 * BB, 256, 0, stream>>>(x, y, part);
        chamfer_reduce_kernel<4><<<256, 256, 0, stream>>>(part, out);
    }
}